// Round 1
// baseline (1298.231 us; speedup 1.0000x reference)
//
#include <hip/hip_runtime.h>
#include <math.h>

typedef float f4 __attribute__((ext_vector_type(4)));

#define BHN 32
#define NN 4096
#define DD 64
#define FF 256
#define EE 64
#define SPLITS 8
#define ROWS_A (NN / SPLITS)   // 512 rows per k-side block
#define TILE_A 32
#define QBLOCKS 16
#define ROWS_B (NN / QBLOCKS)  // 256 rows per q-side block
#define TILE_B 16

// ---------------------------------------------------------------------------
// Kernel A: k-side. Per block: one (bh, split). Computes partial
// kv[f][e] = sum_n k'[n][f] v[n][e] and partial ksum[f] over its row range.
// 512 threads = 8 waves. Wave w: projection rows 4w..4w+3 of each 32-row tile
// (lane owns features 4l..4l+3); accumulation: wave owns features
// [32w,32w+32), lane owns e=lane (kv_acc[32] in registers).
// ---------------------------------------------------------------------------
__global__ __launch_bounds__(512) void perf_kside(
    const float* __restrict__ kin, const float* __restrict__ vin,
    const float* __restrict__ P, float* __restrict__ kv_part,
    float* __restrict__ ksum_part) {
  __shared__ __align__(16) float P_lds[DD][FF];       // 64 KB
  __shared__ __align__(16) float x_lds[TILE_A][DD];   // 8 KB
  __shared__ __align__(16) float v_lds[TILE_A][DD];   // 8 KB
  __shared__ __align__(16) float kp_lds[TILE_A][FF];  // 32 KB
  __shared__ __align__(16) float ks_lds[8][FF];       // 8 KB

  const int t = threadIdx.x;
  const int wave = t >> 6;
  const int lane = t & 63;
  const int bh = blockIdx.x / SPLITS;
  const int split = blockIdx.x % SPLITS;

  {  // load P (64x256 f32) cooperatively, float4
    const f4* Pg = (const f4*)P;
    f4* Pl = (f4*)&P_lds[0][0];
#pragma unroll
    for (int i = 0; i < 8; ++i) Pl[i * 512 + t] = Pg[i * 512 + t];
  }

  float kv_acc[32];
#pragma unroll
  for (int j = 0; j < 32; ++j) kv_acc[j] = 0.f;
  f4 ks4 = {0.f, 0.f, 0.f, 0.f};

  const size_t base = (size_t)bh * NN * DD + (size_t)split * ROWS_A * DD;
  const float* kb = kin + base;
  const float* vb = vin + base;

  for (int it = 0; it < ROWS_A / TILE_A; ++it) {
    __syncthreads();  // protect LDS tiles from previous iteration's readers
    {                 // stage 32 rows of k and v (one float4 per thread each)
      const int fr = t >> 4;
      const int fc = (t & 15) << 2;
      const size_t off = (size_t)(it * TILE_A + fr) * DD + fc;
      *(f4*)&x_lds[fr][fc] = *(const f4*)&kb[off];
      *(f4*)&v_lds[fr][fc] = *(const f4*)&vb[off];
    }
    __syncthreads();

    // ---- projection: rows wave*4..+3, feats 4*lane..+3 ----
    f4 acc[4];
#pragma unroll
    for (int r = 0; r < 4; ++r) acc[r] = (f4){0.f, 0.f, 0.f, 0.f};
#pragma unroll
    for (int db = 0; db < 16; ++db) {
      f4 p0 = *(const f4*)&P_lds[db * 4 + 0][4 * lane];
      f4 p1 = *(const f4*)&P_lds[db * 4 + 1][4 * lane];
      f4 p2 = *(const f4*)&P_lds[db * 4 + 2][4 * lane];
      f4 p3 = *(const f4*)&P_lds[db * 4 + 3][4 * lane];
#pragma unroll
      for (int r = 0; r < 4; ++r) {
        f4 x4 = *(const f4*)&x_lds[wave * 4 + r][db * 4];
        acc[r] += x4.x * p0 + x4.y * p1 + x4.z * p2 + x4.w * p3;
      }
    }
#pragma unroll
    for (int r = 0; r < 4; ++r) {
      float m = fmaxf(fmaxf(acc[r].x, acc[r].y), fmaxf(acc[r].z, acc[r].w));
#pragma unroll
      for (int off = 32; off > 0; off >>= 1)
        m = fmaxf(m, __shfl_xor(m, off, 64));
      f4 kp;
      kp.x = __expf(acc[r].x - m) * 0.0625f;
      kp.y = __expf(acc[r].y - m) * 0.0625f;
      kp.z = __expf(acc[r].z - m) * 0.0625f;
      kp.w = __expf(acc[r].w - m) * 0.0625f;
      ks4 += kp;
      *(f4*)&kp_lds[wave * 4 + r][4 * lane] = kp;
    }
    __syncthreads();

    // ---- accumulate kv: wave's feature slice x lane's e ----
#pragma unroll 4
    for (int r = 0; r < TILE_A; ++r) {
      float vv = v_lds[r][lane];
#pragma unroll
      for (int jb = 0; jb < 8; ++jb) {
        f4 kp4 = *(const f4*)&kp_lds[r][32 * wave + 4 * jb];
        kv_acc[4 * jb + 0] += kp4.x * vv;
        kv_acc[4 * jb + 1] += kp4.y * vv;
        kv_acc[4 * jb + 2] += kp4.z * vv;
        kv_acc[4 * jb + 3] += kp4.w * vv;
      }
    }
  }

  // write kv partial (coalesced per j)
  float* kvp = kv_part + (size_t)(bh * SPLITS + split) * FF * EE;
#pragma unroll
  for (int j = 0; j < 32; ++j) kvp[(32 * wave + j) * EE + lane] = kv_acc[j];

  // ksum partial: cross-wave reduce via LDS
  *(f4*)&ks_lds[wave][4 * lane] = ks4;
  __syncthreads();
  if (t < FF) {
    float s = 0.f;
#pragma unroll
    for (int w = 0; w < 8; ++w) s += ks_lds[w][t];
    ksum_part[(size_t)(bh * SPLITS + split) * FF + t] = s;
  }
}

// ---------------------------------------------------------------------------
// Reduce partials: kv = sum_s kv_part, ksum = sum_s ksum_part
// ---------------------------------------------------------------------------
__global__ __launch_bounds__(256) void perf_reduce(
    const float* __restrict__ kv_part, const float* __restrict__ ksum_part,
    float* __restrict__ kv, float* __restrict__ ksum) {
  const int b = blockIdx.x;
  const int t = threadIdx.x;
  if (b < 2048) {
    const int idx = b * 256 + t;  // 0..524287
    const int bh = idx >> 14;
    const int fe = idx & 16383;
    float s = 0.f;
#pragma unroll
    for (int sp = 0; sp < SPLITS; ++sp)
      s += kv_part[(size_t)(bh * SPLITS + sp) * (FF * EE) + fe];
    kv[idx] = s;
  } else {
    const int idx = (b - 2048) * 256 + t;  // 0..8191
    const int bh = idx >> 8;
    const int f = idx & 255;
    float s = 0.f;
#pragma unroll
    for (int sp = 0; sp < SPLITS; ++sp)
      s += ksum_part[(size_t)(bh * SPLITS + sp) * FF + f];
    ksum[idx] = s;
  }
}

// ---------------------------------------------------------------------------
// Kernel B: q-side. Per block: one (bh, qb). Projects q tiles, computes
// denom = q'.(ksum+1e-6), out = (q' @ kv) / denom. kv cached in registers
// (wave owns feature slice [32w,32w+32), lane owns e=lane); cross-wave
// partial reduction through LDS.
// ---------------------------------------------------------------------------
__global__ __launch_bounds__(512) void perf_qside(
    const float* __restrict__ qin, const float* __restrict__ P,
    const float* __restrict__ kv, const float* __restrict__ ksum,
    float* __restrict__ outg) {
  __shared__ __align__(16) float P_lds[DD][FF];            // 64 KB
  __shared__ __align__(16) float x_lds[TILE_B][DD];        // 4 KB
  __shared__ __align__(16) float qp_lds[TILE_B][FF];       // 16 KB
  __shared__ __align__(16) float part_lds[8][TILE_B][EE];  // 32 KB
  __shared__ __align__(16) float ksum_lds[FF];             // 1 KB
  __shared__ float denom_lds[TILE_B];

  const int t = threadIdx.x;
  const int wave = t >> 6;
  const int lane = t & 63;
  const int bh = blockIdx.x / QBLOCKS;
  const int qb = blockIdx.x % QBLOCKS;

  {
    const f4* Pg = (const f4*)P;
    f4* Pl = (f4*)&P_lds[0][0];
#pragma unroll
    for (int i = 0; i < 8; ++i) Pl[i * 512 + t] = Pg[i * 512 + t];
  }
  if (t < FF) ksum_lds[t] = ksum[bh * FF + t] + 1e-6f;

  // kv slice into registers
  float kv_reg[32];
  {
    const float* kvg = kv + (size_t)bh * FF * EE;
#pragma unroll
    for (int j = 0; j < 32; ++j) kv_reg[j] = kvg[(32 * wave + j) * EE + lane];
  }
  __syncthreads();
  const f4 ksv = *(const f4*)&ksum_lds[4 * lane];

  const float* qp_ptr = qin + (size_t)bh * NN * DD + (size_t)qb * ROWS_B * DD;
  float* ob = outg + (size_t)bh * NN * EE + (size_t)qb * ROWS_B * EE;

  for (int it = 0; it < ROWS_B / TILE_B; ++it) {
    __syncthreads();
    if (t < 256) {  // stage 16 rows of q
      const int fr = t >> 4;
      const int fc = (t & 15) << 2;
      *(f4*)&x_lds[fr][fc] =
          *(const f4*)&qp_ptr[(size_t)(it * TILE_B + fr) * DD + fc];
    }
    __syncthreads();

    // ---- projection: wave rows 2w..2w+1, feats 4*lane..+3 ----
    f4 acc[2];
    acc[0] = (f4){0.f, 0.f, 0.f, 0.f};
    acc[1] = (f4){0.f, 0.f, 0.f, 0.f};
#pragma unroll
    for (int db = 0; db < 16; ++db) {
      f4 p0 = *(const f4*)&P_lds[db * 4 + 0][4 * lane];
      f4 p1 = *(const f4*)&P_lds[db * 4 + 1][4 * lane];
      f4 p2 = *(const f4*)&P_lds[db * 4 + 2][4 * lane];
      f4 p3 = *(const f4*)&P_lds[db * 4 + 3][4 * lane];
#pragma unroll
      for (int r = 0; r < 2; ++r) {
        f4 x4 = *(const f4*)&x_lds[wave * 2 + r][db * 4];
        acc[r] += x4.x * p0 + x4.y * p1 + x4.z * p2 + x4.w * p3;
      }
    }
#pragma unroll
    for (int r = 0; r < 2; ++r) {
      float m = fmaxf(fmaxf(acc[r].x, acc[r].y), fmaxf(acc[r].z, acc[r].w));
#pragma unroll
      for (int off = 32; off > 0; off >>= 1)
        m = fmaxf(m, __shfl_xor(m, off, 64));
      f4 kp;
      kp.x = __expf(acc[r].x - m) * 0.0625f;
      kp.y = __expf(acc[r].y - m) * 0.0625f;
      kp.z = __expf(acc[r].z - m) * 0.0625f;
      kp.w = __expf(acc[r].w - m) * 0.0625f;
      *(f4*)&qp_lds[wave * 2 + r][4 * lane] = kp;
      // denom from registers
      float dp = kp.x * ksv.x + kp.y * ksv.y + kp.z * ksv.z + kp.w * ksv.w;
#pragma unroll
      for (int off = 32; off > 0; off >>= 1) dp += __shfl_xor(dp, off, 64);
      if (lane == 0) denom_lds[wave * 2 + r] = dp;
    }
    __syncthreads();

    // ---- out-GEMM partials over wave's feature slice ----
    float accP[TILE_B];
#pragma unroll
    for (int r = 0; r < TILE_B; ++r) accP[r] = 0.f;
#pragma unroll 4
    for (int r = 0; r < TILE_B; ++r) {
#pragma unroll
      for (int jb = 0; jb < 8; ++jb) {
        f4 qp4 = *(const f4*)&qp_lds[r][32 * wave + 4 * jb];
        accP[r] += qp4.x * kv_reg[4 * jb + 0] + qp4.y * kv_reg[4 * jb + 1] +
                   qp4.z * kv_reg[4 * jb + 2] + qp4.w * kv_reg[4 * jb + 3];
      }
    }
#pragma unroll
    for (int r = 0; r < TILE_B; ++r) part_lds[wave][r][lane] = accP[r];
    __syncthreads();

    // ---- cross-wave reduce + divide + store (1024 outs, 512 threads) ----
#pragma unroll
    for (int i = 0; i < 2; ++i) {
      const int idx = t + i * 512;
      const int r = idx >> 6;
      const int e = idx & 63;
      float s = 0.f;
#pragma unroll
      for (int w = 0; w < 8; ++w) s += part_lds[w][r][e];
      ob[(size_t)(it * TILE_B + r) * EE + e] = s / denom_lds[r];
    }
  }
}

extern "C" void kernel_launch(void* const* d_in, const int* in_sizes, int n_in,
                              void* d_out, int out_size, void* d_ws,
                              size_t ws_size, hipStream_t stream) {
  (void)in_sizes;
  (void)n_in;
  (void)out_size;
  (void)ws_size;
  const float* q = (const float*)d_in[0];
  const float* k = (const float*)d_in[1];
  const float* v = (const float*)d_in[2];
  const float* P = (const float*)d_in[3];
  float* out = (float*)d_out;

  float* kv_part = (float*)d_ws;                               // 32*8*16384 f32
  float* ksum_part = kv_part + (size_t)BHN * SPLITS * FF * EE; // 32*8*256
  float* kv = ksum_part + (size_t)BHN * SPLITS * FF;           // 32*16384
  float* ksum = kv + (size_t)BHN * FF * EE;                    // 32*256

  hipLaunchKernelGGL(perf_kside, dim3(BHN * SPLITS), dim3(512), 0, stream, k, v,
                     P, kv_part, ksum_part);
  hipLaunchKernelGGL(perf_reduce, dim3(2048 + 32), dim3(256), 0, stream,
                     kv_part, ksum_part, kv, ksum);
  hipLaunchKernelGGL(perf_qside, dim3(BHN * QBLOCKS), dim3(512), 0, stream, q,
                     P, kv, ksum, out);
}

// Round 2
// 199.205 us; speedup vs baseline: 6.5171x; 6.5171x over previous
//
#include <hip/hip_runtime.h>
#include <math.h>

typedef float f4 __attribute__((ext_vector_type(4)));
typedef float f32x4 __attribute__((ext_vector_type(4)));
typedef _Float16 h4 __attribute__((ext_vector_type(4)));
typedef _Float16 h8 __attribute__((ext_vector_type(8)));

#define BH 32
#define NN 4096
#define DD 64
#define FF 256
#define EE 64
#define SPLITS 8
#define ROWS_K (NN / SPLITS)  // 512 rows per kside block
#define QB 8
#define ROWS_Q (NN / QB)      // 512 rows per qside block
#define TILE 64               // rows per inner tile
#define ST 72                 // f16 LDS stride for 64-wide rows (pad 8)
#define STF 264               // f16 LDS stride for 256-wide rows (pad 8)

#define MFMA(a, b, c) __builtin_amdgcn_mfma_f32_16x16x32_f16((a), (b), (c), 0, 0, 0)

// ws layout (floats): kv_part[256][16384] | ksum_part[256][1024] |
//                     kvt f16[32][64][256] | ksum f32[32][256]
#define KVPART_F 4194304
#define KSPART_F 262144

// ---------------------------------------------------------------------------
// kside: grid 32*8, 512 thr (8 waves). Per (bh,split): 8 tiles of 64 rows.
// proj: wave w -> row-strip (w&3), f-half (w>>2). kv GEMM: wave w -> f-tiles
// {2w,2w+1} x all 4 e-tiles, fp32 acc persistent.
// ---------------------------------------------------------------------------
__global__ __launch_bounds__(512, 2) void fa_kside(
    const float* __restrict__ kin, const float* __restrict__ vin,
    const float* __restrict__ P, float* __restrict__ kv_part,
    float* __restrict__ ksum_part) {
  __shared__ _Float16 Pt[FF * ST];    // P^T[f][d]
  __shared__ _Float16 kx[TILE * ST];  // k rows [r][d]
  __shared__ _Float16 vrow[TILE * ST];
  __shared__ _Float16 vt[TILE * ST];   // v^T[e][r]
  __shared__ _Float16 kpt[FF * ST];    // kp^T[f][r]
  __shared__ float rowmax2[2][TILE];

  const int t = threadIdx.x;
  const int w = t >> 6, lane = t & 63;
  const int g = lane >> 4, fl = lane & 15;
  const int s = w & 3, nh = w >> 2;
  const int bh = blockIdx.x >> 3, split = blockIdx.x & 7;
  const int bhs = blockIdx.x;
  const int k0 = g * 8;

  {  // stage P^T (f16)
    const f4* Pg4 = (const f4*)P;  // [64][64 f4]
#pragma unroll
    for (int i = 0; i < 8; ++i) {
      int idx = t + i * 512;
      f4 pv = Pg4[idx];
      int d = idx >> 6, f0 = (idx & 63) * 4;
      Pt[(f0 + 0) * ST + d] = (_Float16)pv.x;
      Pt[(f0 + 1) * ST + d] = (_Float16)pv.y;
      Pt[(f0 + 2) * ST + d] = (_Float16)pv.z;
      Pt[(f0 + 3) * ST + d] = (_Float16)pv.w;
    }
  }

  f32x4 kvacc[2][4];
#pragma unroll
  for (int mi = 0; mi < 2; ++mi)
#pragma unroll
    for (int nt = 0; nt < 4; ++nt) kvacc[mi][nt] = (f32x4){0.f, 0.f, 0.f, 0.f};
  float ksum_acc[8] = {0.f, 0.f, 0.f, 0.f, 0.f, 0.f, 0.f, 0.f};

  const size_t base = (size_t)bh * NN * DD + (size_t)split * ROWS_K * DD;

  for (int it = 0; it < ROWS_K / TILE; ++it) {
    const f4* kb4 = (const f4*)(kin + base + (size_t)it * TILE * DD);
    const f4* vb4 = (const f4*)(vin + base + (size_t)it * TILE * DD);
#pragma unroll
    for (int i = 0; i < 2; ++i) {  // stage 64 rows of k,v as f16
      int idx = t + i * 512;
      int r = idx >> 4, c4 = (idx & 15) * 4;
      f4 xv = kb4[idx];
      h4 hk;
      hk.x = (_Float16)xv.x; hk.y = (_Float16)xv.y;
      hk.z = (_Float16)xv.z; hk.w = (_Float16)xv.w;
      *(h4*)&kx[r * ST + c4] = hk;
      f4 vv = vb4[idx];
      h4 hv;
      hv.x = (_Float16)vv.x; hv.y = (_Float16)vv.y;
      hv.z = (_Float16)vv.z; hv.w = (_Float16)vv.w;
      *(h4*)&vrow[r * ST + c4] = hv;
    }
    __syncthreads();  // b1

    // ---- projection: logits[strip s][f-half nh] ----
    const int rA = s * 16 + fl;
    h8 a0 = *(const h8*)&kx[rA * ST + k0];
    h8 a1 = *(const h8*)&kx[rA * ST + 32 + k0];
    f32x4 lac[8];
#pragma unroll
    for (int T = 0; T < 8; ++T) {
      int ncol = (nh * 8 + T) * 16 + fl;
      h8 b0 = *(const h8*)&Pt[ncol * ST + k0];
      h8 b1 = *(const h8*)&Pt[ncol * ST + 32 + k0];
      f32x4 c = {0.f, 0.f, 0.f, 0.f};
      c = MFMA(a0, b0, c);
      c = MFMA(a1, b1, c);
      lac[T] = c;
    }

    // ---- v transpose (vrow -> vt), wave w owns rows 8w..8w+7 ----
    {
      int e = lane, r0v = w * 8;
      h8 tv;
#pragma unroll
      for (int j = 0; j < 8; ++j) tv[j] = vrow[(r0v + j) * ST + e];
      *(h8*)&vt[e * ST + r0v] = tv;
    }

    // ---- rowmax over this wave's f-half ----
    {
      float mx[4];
#pragma unroll
      for (int rg = 0; rg < 4; ++rg) {
        float m = lac[0][rg];
#pragma unroll
        for (int T = 1; T < 8; ++T) m = fmaxf(m, lac[T][rg]);
#pragma unroll
        for (int off = 1; off <= 8; off <<= 1)
          m = fmaxf(m, __shfl_xor(m, off, 64));
        mx[rg] = m;
      }
      if (fl == 0) {
#pragma unroll
        for (int rg = 0; rg < 4; ++rg)
          rowmax2[nh][s * 16 + g * 4 + rg] = mx[rg];
      }
    }
    __syncthreads();  // b2

    // ---- exp, ksum accumulate, store kp^T (f16) ----
    {
      const int r0 = s * 16 + g * 4;
      float mrow[4];
#pragma unroll
      for (int rg = 0; rg < 4; ++rg)
        mrow[rg] = fmaxf(rowmax2[0][r0 + rg], rowmax2[1][r0 + rg]);
#pragma unroll
      for (int T = 0; T < 8; ++T) {
        int ncol = (nh * 8 + T) * 16 + fl;
        h4 kp;
#pragma unroll
        for (int rg = 0; rg < 4; ++rg) {
          float ev = __expf(lac[T][rg] - mrow[rg]) * 0.0625f;
          _Float16 hv = (_Float16)ev;
          ksum_acc[T] += (float)hv;
          kp[rg] = hv;
        }
        *(h4*)&kpt[ncol * ST + r0] = kp;
      }
    }
    __syncthreads();  // b3

    // ---- kv GEMM: kv[f][e] += kp^T @ v ----
    {
      h8 vb0[4], vb1[4];
#pragma unroll
      for (int nt = 0; nt < 4; ++nt) {
        int ec = nt * 16 + fl;
        vb0[nt] = *(const h8*)&vt[ec * ST + k0];
        vb1[nt] = *(const h8*)&vt[ec * ST + 32 + k0];
      }
#pragma unroll
      for (int mi = 0; mi < 2; ++mi) {
        int frow = (2 * w + mi) * 16 + fl;
        h8 ka0 = *(const h8*)&kpt[frow * ST + k0];
        h8 ka1 = *(const h8*)&kpt[frow * ST + 32 + k0];
#pragma unroll
        for (int nt = 0; nt < 4; ++nt) {
          kvacc[mi][nt] = MFMA(ka0, vb0[nt], kvacc[mi][nt]);
          kvacc[mi][nt] = MFMA(ka1, vb1[nt], kvacc[mi][nt]);
        }
      }
    }
  }

  // ---- write kv partial ----
  float* kvp = kv_part + (size_t)bhs * (FF * EE);
#pragma unroll
  for (int mi = 0; mi < 2; ++mi)
#pragma unroll
    for (int nt = 0; nt < 4; ++nt)
#pragma unroll
      for (int rg = 0; rg < 4; ++rg) {
        int f = (2 * w + mi) * 16 + g * 4 + rg;
        int e = nt * 16 + fl;
        kvp[f * EE + e] = kvacc[mi][nt][rg];
      }

  // ---- write ksum partial: layout [bhs][w][T*16+fl] ----
#pragma unroll
  for (int T = 0; T < 8; ++T) {
    float sg = ksum_acc[T];
    sg += __shfl_xor(sg, 16, 64);
    sg += __shfl_xor(sg, 32, 64);
    if (lane < 16)
      ksum_part[(size_t)bhs * 1024 + w * 128 + T * 16 + lane] = sg;
  }
}

// ---------------------------------------------------------------------------
// reduce: 32 blocks (one per bh). kv = sum_splits -> f16 transposed kv^T[e][f];
// ksum = sum + 1e-6.
// ---------------------------------------------------------------------------
__global__ __launch_bounds__(256) void fa_reduce(
    const float* __restrict__ kv_part, const float* __restrict__ ksum_part,
    _Float16* __restrict__ kvt_g, float* __restrict__ ksum_g) {
  __shared__ _Float16 lds[EE * STF];
  const int bh = blockIdx.x, t = threadIdx.x;
  for (int i = 0; i < 64; ++i) {
    int idx = i * 256 + t;
    int f = idx >> 6, e = idx & 63;
    float s = 0.f;
#pragma unroll
    for (int sp = 0; sp < SPLITS; ++sp)
      s += kv_part[(size_t)(bh * SPLITS + sp) * (FF * EE) + idx];
    lds[e * STF + f] = (_Float16)s;
  }
  {
    int f = t;
    float s = 0.f;
#pragma unroll
    for (int sp = 0; sp < SPLITS; ++sp)
#pragma unroll
      for (int j = 0; j < 4; ++j)
        s += ksum_part[(size_t)(bh * SPLITS + sp) * 1024 +
                       ((f >> 7) * 4 + j) * 128 + (f & 127)];
    ksum_g[bh * FF + f] = s + 1e-6f;
  }
  __syncthreads();
  unsigned int* og = (unsigned int*)kvt_g + (size_t)bh * 8192;
  for (int i = 0; i < 32; ++i) {
    int idx = i * 256 + t;
    int e = idx >> 7, fp = (idx & 127) * 2;
    og[idx] = *(const unsigned int*)&lds[e * STF + fp];
  }
}

// ---------------------------------------------------------------------------
// qside: grid 32*8, 512 thr. Per (bh,qb): 8 tiles of 64 rows.
// proj like kside; denom in-lane from C-layout; out GEMM from qp^ (row-major
// LDS, no transpose needed for A) x kv^T (staged f16).
// ---------------------------------------------------------------------------
__global__ __launch_bounds__(512, 2) void fa_qside(
    const float* __restrict__ qin, const float* __restrict__ P,
    const _Float16* __restrict__ kvt_g, const float* __restrict__ ksum_g,
    float* __restrict__ out) {
  __shared__ _Float16 Pt[FF * ST];
  __shared__ _Float16 qx[TILE * ST];
  __shared__ _Float16 qpt[TILE * STF];  // qp[row][f]
  __shared__ _Float16 kvt[EE * STF];    // kv^T[e][f]
  __shared__ float rowmax2[2][TILE];
  __shared__ float denp[2][TILE];

  const int t = threadIdx.x;
  const int w = t >> 6, lane = t & 63;
  const int g = lane >> 4, fl = lane & 15;
  const int s = w & 3, nh = w >> 2;
  const int bh = blockIdx.x >> 3, qb = blockIdx.x & 7;
  const int k0 = g * 8;

  {  // stage P^T
    const f4* Pg4 = (const f4*)P;
#pragma unroll
    for (int i = 0; i < 8; ++i) {
      int idx = t + i * 512;
      f4 pv = Pg4[idx];
      int d = idx >> 6, f0 = (idx & 63) * 4;
      Pt[(f0 + 0) * ST + d] = (_Float16)pv.x;
      Pt[(f0 + 1) * ST + d] = (_Float16)pv.y;
      Pt[(f0 + 2) * ST + d] = (_Float16)pv.z;
      Pt[(f0 + 3) * ST + d] = (_Float16)pv.w;
    }
  }
  {  // stage kv^T f16
    const h8* src = (const h8*)(kvt_g + (size_t)bh * FF * EE);
#pragma unroll
    for (int i = 0; i < 4; ++i) {
      int idx = t + i * 512;  // 2048 h8
      int e = idx >> 5, f0 = (idx & 31) * 8;
      *(h8*)&kvt[e * STF + f0] = src[idx];
    }
  }
  float ksr[8];
#pragma unroll
  for (int T = 0; T < 8; ++T)
    ksr[T] = ksum_g[bh * FF + nh * 128 + T * 16 + fl];

  const size_t base = (size_t)bh * NN * DD + (size_t)qb * ROWS_Q * DD;
  float* ob = out + (size_t)bh * NN * EE + (size_t)qb * ROWS_Q * EE;

  for (int it = 0; it < ROWS_Q / TILE; ++it) {
    const f4* qb4 = (const f4*)(qin + base + (size_t)it * TILE * DD);
#pragma unroll
    for (int i = 0; i < 2; ++i) {
      int idx = t + i * 512;
      int r = idx >> 4, c4 = (idx & 15) * 4;
      f4 xv = qb4[idx];
      h4 hq;
      hq.x = (_Float16)xv.x; hq.y = (_Float16)xv.y;
      hq.z = (_Float16)xv.z; hq.w = (_Float16)xv.w;
      *(h4*)&qx[r * ST + c4] = hq;
    }
    __syncthreads();  // b1

    const int rA = s * 16 + fl;
    h8 a0 = *(const h8*)&qx[rA * ST + k0];
    h8 a1 = *(const h8*)&qx[rA * ST + 32 + k0];
    f32x4 lac[8];
#pragma unroll
    for (int T = 0; T < 8; ++T) {
      int ncol = (nh * 8 + T) * 16 + fl;
      h8 b0 = *(const h8*)&Pt[ncol * ST + k0];
      h8 b1 = *(const h8*)&Pt[ncol * ST + 32 + k0];
      f32x4 c = {0.f, 0.f, 0.f, 0.f};
      c = MFMA(a0, b0, c);
      c = MFMA(a1, b1, c);
      lac[T] = c;
    }
    {
      float mx[4];
#pragma unroll
      for (int rg = 0; rg < 4; ++rg) {
        float m = lac[0][rg];
#pragma unroll
        for (int T = 1; T < 8; ++T) m = fmaxf(m, lac[T][rg]);
#pragma unroll
        for (int off = 1; off <= 8; off <<= 1)
          m = fmaxf(m, __shfl_xor(m, off, 64));
        mx[rg] = m;
      }
      if (fl == 0) {
#pragma unroll
        for (int rg = 0; rg < 4; ++rg)
          rowmax2[nh][s * 16 + g * 4 + rg] = mx[rg];
      }
    }
    __syncthreads();  // b2

    {  // exp + denom partial + store qp (f16)
      const int r0 = s * 16 + g * 4;
      float mrow[4];
#pragma unroll
      for (int rg = 0; rg < 4; ++rg)
        mrow[rg] = fmaxf(rowmax2[0][r0 + rg], rowmax2[1][r0 + rg]);
      float den[4] = {0.f, 0.f, 0.f, 0.f};
#pragma unroll
      for (int T = 0; T < 8; ++T) {
        int ncol = (nh * 8 + T) * 16 + fl;
#pragma unroll
        for (int rg = 0; rg < 4; ++rg) {
          float ev = __expf(lac[T][rg] - mrow[rg]) * 0.0625f;
          _Float16 hv = (_Float16)ev;
          den[rg] += (float)hv * ksr[T];
          qpt[(r0 + rg) * STF + ncol] = hv;
        }
      }
#pragma unroll
      for (int rg = 0; rg < 4; ++rg) {
#pragma unroll
        for (int off = 1; off <= 8; off <<= 1)
          den[rg] += __shfl_xor(den[rg], off, 64);
      }
      if (fl == 0) {
#pragma unroll
        for (int rg = 0; rg < 4; ++rg) denp[nh][r0 + rg] = den[rg];
      }
    }
    __syncthreads();  // b3

    {  // out GEMM: rows strip s, e-half nh
      f32x4 oacc[2];
      oacc[0] = (f32x4){0.f, 0.f, 0.f, 0.f};
      oacc[1] = (f32x4){0.f, 0.f, 0.f, 0.f};
      const int row = s * 16 + fl;
#pragma unroll
      for (int kst = 0; kst < 8; ++kst) {
        h8 aq = *(const h8*)&qpt[row * STF + kst * 32 + k0];
#pragma unroll
        for (int ni = 0; ni < 2; ++ni) {
          int ec = (nh * 2 + ni) * 16 + fl;
          h8 bq = *(const h8*)&kvt[ec * STF + kst * 32 + k0];
          oacc[ni] = MFMA(aq, bq, oacc[ni]);
        }
      }
      const int r0 = s * 16 + g * 4;
      float* obt = ob + (size_t)it * TILE * EE;
#pragma unroll
      for (int rg = 0; rg < 4; ++rg) {
        int ro = r0 + rg;
        float dn = denp[0][ro] + denp[1][ro];
        float inv = 1.0f / dn;
#pragma unroll
        for (int ni = 0; ni < 2; ++ni) {
          int e = (nh * 2 + ni) * 16 + fl;
          obt[ro * EE + e] = oacc[ni][rg] * inv;
        }
      }
    }
  }
}

extern "C" void kernel_launch(void* const* d_in, const int* in_sizes, int n_in,
                              void* d_out, int out_size, void* d_ws,
                              size_t ws_size, hipStream_t stream) {
  (void)in_sizes;
  (void)n_in;
  (void)out_size;
  (void)ws_size;
  const float* q = (const float*)d_in[0];
  const float* k = (const float*)d_in[1];
  const float* v = (const float*)d_in[2];
  const float* P = (const float*)d_in[3];
  float* out = (float*)d_out;

  float* kv_part = (float*)d_ws;
  float* ksum_part = kv_part + KVPART_F;
  _Float16* kvt_g = (_Float16*)(ksum_part + KSPART_F);
  float* ksum_g = (float*)(kvt_g + BH * FF * EE);

  hipLaunchKernelGGL(fa_kside, dim3(BH * SPLITS), dim3(512), 0, stream, k, v, P,
                     kv_part, ksum_part);
  hipLaunchKernelGGL(fa_reduce, dim3(BH), dim3(256), 0, stream, kv_part,
                     ksum_part, kvt_g, ksum_g);
  hipLaunchKernelGGL(fa_qside, dim3(BH * QB), dim3(512), 0, stream, q, P, kvt_g,
                     ksum_g, out);
}

// Round 3
// 176.017 us; speedup vs baseline: 7.3756x; 1.1317x over previous
//
#include <hip/hip_runtime.h>
#include <math.h>

typedef float f4 __attribute__((ext_vector_type(4)));
typedef float f32x4 __attribute__((ext_vector_type(4)));
typedef _Float16 h4 __attribute__((ext_vector_type(4)));
typedef _Float16 h8 __attribute__((ext_vector_type(8)));

#define BH 32
#define NN 4096
#define DD 64
#define FF 256
#define EE 64
#define SPLITS 8
#define ROWS_K 512
#define QB 8
#define ROWS_Q 512
#define ST 72    // Pt stride (f16)
#define SK 136   // kside kpt/vt row stride (128 rows + 8 pad)
#define STF 264  // qside qpt/kvt stride (256 + 8 pad)

#define MFMA(a, b, c) __builtin_amdgcn_mfma_f32_16x16x32_f16((a), (b), (c), 0, 0, 0)

__device__ inline h8 cvt2(f4 x0, f4 x1) {
  h8 r;
  r[0] = (_Float16)x0.x; r[1] = (_Float16)x0.y;
  r[2] = (_Float16)x0.z; r[3] = (_Float16)x0.w;
  r[4] = (_Float16)x1.x; r[5] = (_Float16)x1.y;
  r[6] = (_Float16)x1.z; r[7] = (_Float16)x1.w;
  return r;
}

// ---------------------------------------------------------------------------
// kside: grid 32*8, 512 thr (8 waves). Tile = 128 rows, wave owns a 16-row
// strip: full-f projection + in-wave rowmax/exp (no cross-wave exchange).
// Only 2 barriers per tile (kpt/vt RAW, WAR). kv GEMM: wave owns 32-f slice.
// ---------------------------------------------------------------------------
__global__ __launch_bounds__(512, 2) void fa_kside(
    const float* __restrict__ kin, const float* __restrict__ vin,
    const float* __restrict__ P, float* __restrict__ kv_part,
    float* __restrict__ ksum_part) {
  __shared__ _Float16 Pt[FF * ST];    // 36.9 KB  P^T[f][d]
  __shared__ _Float16 kpt[FF * SK];   // 69.6 KB  kp^T[f][row]
  __shared__ _Float16 vt[EE * SK];    // 17.4 KB  v^T[e][row]
  __shared__ float ks_lds[8 * FF];    // 8 KB

  const int t = threadIdx.x;
  const int w = t >> 6, lane = t & 63;
  const int g = lane >> 4, fl = lane & 15;
  const int bh = blockIdx.x >> 3, split = blockIdx.x & 7;
  const int bhs = blockIdx.x;
  const int k0 = g * 8;

  {  // stage P^T (f16)
    const f4* Pg4 = (const f4*)P;
#pragma unroll
    for (int i = 0; i < 8; ++i) {
      int idx = t + i * 512;
      f4 pv = Pg4[idx];
      int d = idx >> 6, f0 = (idx & 63) * 4;
      Pt[(f0 + 0) * ST + d] = (_Float16)pv.x;
      Pt[(f0 + 1) * ST + d] = (_Float16)pv.y;
      Pt[(f0 + 2) * ST + d] = (_Float16)pv.z;
      Pt[(f0 + 3) * ST + d] = (_Float16)pv.w;
    }
  }

  f32x4 kvacc[2][4];
#pragma unroll
  for (int mi = 0; mi < 2; ++mi)
#pragma unroll
    for (int nt = 0; nt < 4; ++nt) kvacc[mi][nt] = (f32x4){0.f, 0.f, 0.f, 0.f};
  float ksum_acc[16];
#pragma unroll
  for (int T = 0; T < 16; ++T) ksum_acc[T] = 0.f;

  const size_t base = (size_t)bh * NN * DD + (size_t)split * ROWS_K * DD;
  __syncthreads();  // Pt ready

  for (int tile = 0; tile < 4; ++tile) {
    if (tile) __syncthreads();  // WAR: previous GEMM reads done
    const int r0g = tile * 128 + w * 16;

    // A fragments of k directly from global (row = r0g+fl, d = k-halves)
    const float* krow = kin + base + (size_t)(r0g + fl) * DD;
    h8 a0 = cvt2(*(const f4*)&krow[k0], *(const f4*)&krow[k0 + 4]);
    h8 a1 = cvt2(*(const f4*)&krow[32 + k0], *(const f4*)&krow[32 + k0 + 4]);

    // v^T staging: lane owns e=lane, wave's 16 rows (coalesced per j)
    {
      const float* vb = vin + base + (size_t)r0g * DD + lane;
      h8 tv0, tv1;
#pragma unroll
      for (int j = 0; j < 8; ++j) tv0[j] = (_Float16)vb[j * DD];
#pragma unroll
      for (int j = 0; j < 8; ++j) tv1[j] = (_Float16)vb[(8 + j) * DD];
      *(h8*)&vt[lane * SK + w * 16] = tv0;
      *(h8*)&vt[lane * SK + w * 16 + 8] = tv1;
    }

    // projection: full 256 features for this wave's strip
    f32x4 lac[16];
#pragma unroll
    for (int T = 0; T < 16; ++T) {
      int ncol = T * 16 + fl;
      h8 b0 = *(const h8*)&Pt[ncol * ST + k0];
      h8 b1 = *(const h8*)&Pt[ncol * ST + 32 + k0];
      f32x4 c = {0.f, 0.f, 0.f, 0.f};
      c = MFMA(a0, b0, c);
      c = MFMA(a1, b1, c);
      lac[T] = c;
    }

    // in-wave rowmax
    float mrow[4];
#pragma unroll
    for (int rg = 0; rg < 4; ++rg) {
      float m = lac[0][rg];
#pragma unroll
      for (int T = 1; T < 16; ++T) m = fmaxf(m, lac[T][rg]);
#pragma unroll
      for (int off = 1; off <= 8; off <<= 1)
        m = fmaxf(m, __shfl_xor(m, off, 64));
      mrow[rg] = m;
    }

    // exp + kp^T write + ksum accumulate
#pragma unroll
    for (int T = 0; T < 16; ++T) {
      int ncol = T * 16 + fl;
      h4 kp;
#pragma unroll
      for (int rg = 0; rg < 4; ++rg) {
        float ev = __expf(lac[T][rg] - mrow[rg]) * 0.0625f;
        _Float16 hv = (_Float16)ev;
        ksum_acc[T] += (float)hv;
        kp[rg] = hv;
      }
      *(h4*)&kpt[ncol * SK + w * 16 + g * 4] = kp;
    }
    __syncthreads();  // kpt + vt ready

    // kv GEMM: wave owns f-tiles {2w,2w+1} x 4 e-tiles, k = 128 rows
#pragma unroll
    for (int kst = 0; kst < 4; ++kst) {
      h8 vbf[4];
#pragma unroll
      for (int nt = 0; nt < 4; ++nt)
        vbf[nt] = *(const h8*)&vt[(nt * 16 + fl) * SK + kst * 32 + k0];
#pragma unroll
      for (int mi = 0; mi < 2; ++mi) {
        h8 ka = *(const h8*)&kpt[((2 * w + mi) * 16 + fl) * SK + kst * 32 + k0];
#pragma unroll
        for (int nt = 0; nt < 4; ++nt)
          kvacc[mi][nt] = MFMA(ka, vbf[nt], kvacc[mi][nt]);
      }
    }
  }

  // write kv partial
  float* kvp = kv_part + (size_t)bhs * (FF * EE);
#pragma unroll
  for (int mi = 0; mi < 2; ++mi)
#pragma unroll
    for (int nt = 0; nt < 4; ++nt)
#pragma unroll
      for (int rg = 0; rg < 4; ++rg) {
        int f = (2 * w + mi) * 16 + g * 4 + rg;
        int e = nt * 16 + fl;
        kvp[f * EE + e] = kvacc[mi][nt][rg];
      }

  // ksum partial: reduce over g in-wave, then cross-wave via LDS
#pragma unroll
  for (int T = 0; T < 16; ++T) {
    float s = ksum_acc[T];
    s += __shfl_xor(s, 16, 64);
    s += __shfl_xor(s, 32, 64);
    if (lane < 16) ks_lds[w * FF + T * 16 + lane] = s;
  }
  __syncthreads();
  if (t < FF) {
    float s = 0.f;
#pragma unroll
    for (int wi = 0; wi < 8; ++wi) s += ks_lds[wi * FF + t];
    ksum_part[(size_t)bhs * FF + t] = s;
  }
}

// ---------------------------------------------------------------------------
// reduce: 544 blocks x 256 thr (was 32 — grid-starved). Blocks 0..511: one
// (bh, 16-f-slice) each, vectorized sum + LDS transpose -> kvt f16 [e][f].
// Blocks 512..543: ksum.
// ---------------------------------------------------------------------------
__global__ __launch_bounds__(256) void fa_reduce(
    const float* __restrict__ kv_part, const float* __restrict__ ksum_part,
    _Float16* __restrict__ kvt_g, float* __restrict__ ksum_g) {
  __shared__ _Float16 tl[EE * 18];
  const int b = blockIdx.x, t = threadIdx.x;
  if (b < 512) {
    const int bh = b >> 4, c = b & 15;
#pragma unroll
    for (int i = 0; i < 4; ++i) {
      int idx = i * 256 + t;
      int fr = idx >> 6, e = idx & 63;
      float s = 0.f;
#pragma unroll
      for (int sp = 0; sp < SPLITS; ++sp)
        s += kv_part[(size_t)(bh * SPLITS + sp) * (FF * EE) + (c * 16 + fr) * EE + e];
      tl[e * 18 + fr] = (_Float16)s;
    }
    __syncthreads();
    unsigned int* og = (unsigned int*)kvt_g + (size_t)bh * 8192;
#pragma unroll
    for (int i = 0; i < 2; ++i) {
      int idx = i * 256 + t;
      int e = idx >> 3, fp = (idx & 7) * 2;
      og[e * 128 + c * 8 + (idx & 7)] = *(unsigned int*)&tl[e * 18 + fp];
    }
  } else {
    const int bh = b - 512;
    float s = 0.f;
#pragma unroll
    for (int sp = 0; sp < SPLITS; ++sp)
      s += ksum_part[(size_t)(bh * SPLITS + sp) * FF + t];
    ksum_g[bh * FF + t] = s + 1e-6f;
  }
}

// ---------------------------------------------------------------------------
// qside: grid 32*8, 512 thr. ZERO inner-loop barriers: wave owns 16-row
// strips; q A-frags direct from global; rowmax/exp/denom in-wave; C->A
// transpose through wave-private LDS region; kvt/Pt read-only shared.
// ---------------------------------------------------------------------------
__global__ __launch_bounds__(512, 2) void fa_qside(
    const float* __restrict__ qin, const float* __restrict__ P,
    const _Float16* __restrict__ kvt_g, const float* __restrict__ ksum_g,
    float* __restrict__ out) {
  __shared__ _Float16 Pt[FF * ST];        // 36.9 KB
  __shared__ _Float16 kvt[EE * STF];      // 33.8 KB kv^T[e][f]
  __shared__ _Float16 qpt[8 * 16 * STF];  // 67.6 KB wave-private qp[row][f]

  const int t = threadIdx.x;
  const int w = t >> 6, lane = t & 63;
  const int g = lane >> 4, fl = lane & 15;
  const int bh = blockIdx.x >> 3, qb = blockIdx.x & 7;
  const int k0 = g * 8;

  {  // stage P^T
    const f4* Pg4 = (const f4*)P;
#pragma unroll
    for (int i = 0; i < 8; ++i) {
      int idx = t + i * 512;
      f4 pv = Pg4[idx];
      int d = idx >> 6, f0 = (idx & 63) * 4;
      Pt[(f0 + 0) * ST + d] = (_Float16)pv.x;
      Pt[(f0 + 1) * ST + d] = (_Float16)pv.y;
      Pt[(f0 + 2) * ST + d] = (_Float16)pv.z;
      Pt[(f0 + 3) * ST + d] = (_Float16)pv.w;
    }
  }
  {  // stage kv^T
    const h8* src = (const h8*)(kvt_g + (size_t)bh * FF * EE);
#pragma unroll
    for (int i = 0; i < 4; ++i) {
      int idx = t + i * 512;
      int e = idx >> 5, f0 = (idx & 31) * 8;
      *(h8*)&kvt[e * STF + f0] = src[idx];
    }
  }
  float ksr[16];
#pragma unroll
  for (int T = 0; T < 16; ++T) ksr[T] = ksum_g[bh * FF + T * 16 + fl];
  __syncthreads();  // the only barrier

  _Float16* myqpt = qpt + w * 16 * STF;
  const size_t base = (size_t)bh * NN * DD + (size_t)qb * ROWS_Q * DD;
  float* ob = out + (size_t)bh * NN * EE + (size_t)qb * ROWS_Q * EE;

  for (int st = 0; st < 4; ++st) {
    const int r0g = st * 128 + w * 16;
    const float* qrow = qin + base + (size_t)(r0g + fl) * DD;
    h8 a0 = cvt2(*(const f4*)&qrow[k0], *(const f4*)&qrow[k0 + 4]);
    h8 a1 = cvt2(*(const f4*)&qrow[32 + k0], *(const f4*)&qrow[32 + k0 + 4]);

    f32x4 lac[16];
#pragma unroll
    for (int T = 0; T < 16; ++T) {
      int ncol = T * 16 + fl;
      h8 b0 = *(const h8*)&Pt[ncol * ST + k0];
      h8 b1 = *(const h8*)&Pt[ncol * ST + 32 + k0];
      f32x4 c = {0.f, 0.f, 0.f, 0.f};
      c = MFMA(a0, b0, c);
      c = MFMA(a1, b1, c);
      lac[T] = c;
    }

    float mrow[4];
#pragma unroll
    for (int rg = 0; rg < 4; ++rg) {
      float m = lac[0][rg];
#pragma unroll
      for (int T = 1; T < 16; ++T) m = fmaxf(m, lac[T][rg]);
#pragma unroll
      for (int off = 1; off <= 8; off <<= 1)
        m = fmaxf(m, __shfl_xor(m, off, 64));
      mrow[rg] = m;
    }

    float den[4] = {0.f, 0.f, 0.f, 0.f};
#pragma unroll
    for (int T = 0; T < 16; ++T) {
      int ncol = T * 16 + fl;
#pragma unroll
      for (int rg = 0; rg < 4; ++rg) {
        float ev = __expf(lac[T][rg] - mrow[rg]) * 0.0625f;
        _Float16 hv = (_Float16)ev;
        den[rg] += (float)hv * ksr[T];
        myqpt[(g * 4 + rg) * STF + ncol] = hv;
      }
    }
#pragma unroll
    for (int rg = 0; rg < 4; ++rg) {
#pragma unroll
      for (int off = 1; off <= 8; off <<= 1)
        den[rg] += __shfl_xor(den[rg], off, 64);
    }

    // out GEMM: A = myqpt (wave-private, in-order DS pipeline), B = kvt
    f32x4 oacc[4];
#pragma unroll
    for (int nt = 0; nt < 4; ++nt) oacc[nt] = (f32x4){0.f, 0.f, 0.f, 0.f};
#pragma unroll
    for (int kst = 0; kst < 8; ++kst) {
      h8 aq = *(const h8*)&myqpt[fl * STF + kst * 32 + k0];
#pragma unroll
      for (int nt = 0; nt < 4; ++nt) {
        h8 bq = *(const h8*)&kvt[(nt * 16 + fl) * STF + kst * 32 + k0];
        oacc[nt] = MFMA(aq, bq, oacc[nt]);
      }
    }

    float* obt = ob + (size_t)r0g * EE;
#pragma unroll
    for (int rg = 0; rg < 4; ++rg) {
      float inv = 1.0f / den[rg];
#pragma unroll
      for (int nt = 0; nt < 4; ++nt) {
        int e = nt * 16 + fl;
        obt[(g * 4 + rg) * EE + e] = oacc[nt][rg] * inv;
      }
    }
  }
}

extern "C" void kernel_launch(void* const* d_in, const int* in_sizes, int n_in,
                              void* d_out, int out_size, void* d_ws,
                              size_t ws_size, hipStream_t stream) {
  (void)in_sizes;
  (void)n_in;
  (void)out_size;
  (void)ws_size;
  const float* q = (const float*)d_in[0];
  const float* k = (const float*)d_in[1];
  const float* v = (const float*)d_in[2];
  const float* P = (const float*)d_in[3];
  float* out = (float*)d_out;

  float* kv_part = (float*)d_ws;                    // 256*16384 f32 = 16 MB
  float* ksum_part = kv_part + 256 * 16384;         // 256*256 f32
  _Float16* kvt_g = (_Float16*)(ksum_part + 256 * 256);  // 32*16384 f16
  float* ksum_g = (float*)(kvt_g + 32 * 16384);          // 32*256 f32

  hipLaunchKernelGGL(fa_kside, dim3(BH * SPLITS), dim3(512), 0, stream, k, v, P,
                     kv_part, ksum_part);
  hipLaunchKernelGGL(fa_reduce, dim3(544), dim3(256), 0, stream, kv_part,
                     ksum_part, kvt_g, ksum_g);
  hipLaunchKernelGGL(fa_qside, dim3(BH * QB), dim3(512), 0, stream, q, P, kvt_g,
                     ksum_g, out);
}